// Round 2
// baseline (3863.741 us; speedup 1.0000x reference)
//
#include <hip/hip_runtime.h>
#include <stdint.h>

// ---------------------------------------------------------------------------
// Masker: 3-layer MLP head (fp32 GEMM + BatchNorm(+ReLU)) then K=1024
// Gumbel-softmax scan with z = running max.
// Round 2: switch PRNG to JAX *partitionable* threefry semantics
// (jax_threefry_partitionable=True, default since JAX 0.4.36):
//   split(key)[t]    = both words of threefry(key; 0, t)
//   bits32(sub)[i]   = o0 ^ o1 of threefry(sub; 0, i)   (i = flat index)
// Scan: 128 blocks (one row each), key chain pipelined by a dedicated wave.
// ---------------------------------------------------------------------------

// ------------------------- Threefry-2x32-20 (JAX) --------------------------
__device__ __forceinline__ uint32_t rotl32(uint32_t v, int r) {
  return (v << r) | (v >> (32 - r));
}

__device__ __forceinline__ void tf2x32(uint32_t k0, uint32_t k1,
                                       uint32_t x0, uint32_t x1,
                                       uint32_t& o0, uint32_t& o1) {
  uint32_t k2 = k0 ^ k1 ^ 0x1BD11BDAu;
  x0 += k0; x1 += k1;
#define TFR(r) { x0 += x1; x1 = rotl32(x1, (r)); x1 ^= x0; }
  TFR(13) TFR(15) TFR(26) TFR(6)   x0 += k1; x1 += k2 + 1u;
  TFR(17) TFR(29) TFR(16) TFR(24)  x0 += k2; x1 += k0 + 2u;
  TFR(13) TFR(15) TFR(26) TFR(6)   x0 += k0; x1 += k1 + 3u;
  TFR(17) TFR(29) TFR(16) TFR(24)  x0 += k1; x1 += k2 + 4u;
  TFR(13) TFR(15) TFR(26) TFR(6)   x0 += k2; x1 += k0 + 5u;
#undef TFR
  o0 = x0; o1 = x1;
}

// u = max((bits>>9 | 1.0f_bits) - 1, tiny)  (== JAX uniform(tiny, 1))
// g = -ln(-ln u) = fma(-ln2, log2(-log2 u), -ln(ln 2))
__device__ __forceinline__ float gumbel_from_bits(uint32_t bits) {
  uint32_t fb = (bits >> 9) | 0x3f800000u;
  float u = __uint_as_float(fb) - 1.0f;
  u = fmaxf(u, 1.17549435e-38f);
  float l = __log2f(u);            // log2(u) < 0
  float t = __log2f(-l);           // log2(-log2 u)
  return fmaf(-0.69314718055994531f, t, 0.36651292058166435f);
}

// ------------------------------- GEMM --------------------------------------
// C_partial[slice][b][n] = sum_{k in chunk} A[b,k] * W[n,k]
// A: (128, K) row-major, W: (N, K) row-major. Tile 128x128, BK=16.
#define BK 16

__global__ __launch_bounds__(256) void gemm_splitk(
    const float* __restrict__ A, const float* __restrict__ W,
    float* __restrict__ P, int K, int N, int kchunk)
{
  __shared__ float sA[BK][132];   // [k][b], +4 pad keeps 16B alignment
  __shared__ float sW[BK][132];   // [k][n]
  const int tid = threadIdx.x;
  const int n0 = blockIdx.x * 128;
  const int k0 = blockIdx.y * kchunk;
  const int tx = tid & 15;        // n-group: n = n0 + tx*8 ..
  const int ty = tid >> 4;        // b-group: b = ty*8 ..

  float acc[8][8];
#pragma unroll
  for (int i = 0; i < 8; i++)
#pragma unroll
    for (int j = 0; j < 8; j++) acc[i][j] = 0.f;

  for (int kt = k0; kt < k0 + kchunk; kt += BK) {
#pragma unroll
    for (int i = 0; i < 2; i++) {
      int q = tid * 2 + i;        // 0..511
      int row = q >> 2;           // 0..127
      int kk = (q & 3) * 4;       // 0,4,8,12
      float4 av = *(const float4*)(A + (size_t)row * K + kt + kk);
      sA[kk + 0][row] = av.x; sA[kk + 1][row] = av.y;
      sA[kk + 2][row] = av.z; sA[kk + 3][row] = av.w;
      float4 wv = *(const float4*)(W + (size_t)(n0 + row) * K + kt + kk);
      sW[kk + 0][row] = wv.x; sW[kk + 1][row] = wv.y;
      sW[kk + 2][row] = wv.z; sW[kk + 3][row] = wv.w;
    }
    __syncthreads();
#pragma unroll
    for (int kk = 0; kk < BK; kk++) {
      float a[8], w[8];
#pragma unroll
      for (int i = 0; i < 8; i++) a[i] = sA[kk][ty * 8 + i];
#pragma unroll
      for (int j = 0; j < 8; j++) w[j] = sW[kk][tx * 8 + j];
#pragma unroll
      for (int i = 0; i < 8; i++)
#pragma unroll
        for (int j = 0; j < 8; j++)
          acc[i][j] = fmaf(a[i], w[j], acc[i][j]);
    }
    __syncthreads();
  }

  float* Ps = P + (size_t)blockIdx.y * 128 * N;
#pragma unroll
  for (int i = 0; i < 8; i++) {
    int b = ty * 8 + i;
#pragma unroll
    for (int j = 0; j < 8; j += 4) {
      float4 v = make_float4(acc[i][j], acc[i][j + 1], acc[i][j + 2], acc[i][j + 3]);
      *(float4*)(Ps + (size_t)b * N + n0 + tx * 8 + j) = v;
    }
  }
}

// ------------------------------ BatchNorm ----------------------------------
// x[r,c] = bias[c] + sum_s P[s][r][c]; torch-style training BN over batch dim
// (biased variance), optional affine + relu. One thread per column.
__global__ void bn_kernel(const float* __restrict__ P, int nsl, int N,
                          const float* __restrict__ bias,
                          const float* __restrict__ gamma,
                          const float* __restrict__ beta,
                          float* __restrict__ out, int relu)
{
  int c = blockIdx.x * 256 + threadIdx.x;
  if (c >= N) return;
  float bc = bias ? bias[c] : 0.f;
  float s = 0.f, s2 = 0.f;
  for (int r = 0; r < 128; r++) {
    float x = bc;
    for (int t = 0; t < nsl; t++) x += P[(size_t)t * 128 * N + (size_t)r * N + c];
    s += x; s2 += x * x;
  }
  float mu = s * (1.f / 128.f);
  float var = s2 * (1.f / 128.f) - mu * mu;
  float rstd = rsqrtf(var + 1e-5f);
  float ga = gamma ? gamma[c] : 1.f;
  float be = beta ? beta[c] : 0.f;
  float scale = rstd * ga;
  float shift = be - mu * scale;
  for (int r = 0; r < 128; r++) {
    float x = bc;
    for (int t = 0; t < nsl; t++) x += P[(size_t)t * 128 * N + (size_t)r * N + c];
    float y = fmaf(x, scale, shift);
    if (relu) y = fmaxf(y, 0.f);
    out[(size_t)r * N + c] = y;
  }
}

// ----------------------------- Gumbel scan ---------------------------------
// One block per row. 512 work threads (8 waves) x 4 columns = 2048 elements.
// Partitionable threefry: element (row, c) uses counter (0, row*2048+c),
// bits = o0 ^ o1. Wave 8 (threads 512..575, first two lanes) runs the serial
// key chain one iteration ahead (hidden behind the softmax barriers):
//   split(key)[0] -> next key, split(key)[1] -> sub for next iteration,
//   where split(key)[t] = threefry(key; 0, t) (both output words).
#define GT 512
#define NCOL 4

__global__ __launch_bounds__(576) void gumbel_kernel(
    const float* __restrict__ logits, float* __restrict__ z_out)
{
  const int tid = threadIdx.x;
  const int row = blockIdx.x;             // 0..127
  const int wid = tid >> 6;
  const int lane = tid & 63;
  const bool worker = tid < GT;

  __shared__ uint32_t s_kc[2][2];         // [parity][word] current key
  __shared__ uint32_t s_sub[2][2];        // [parity][word] subkey for iter
  __shared__ float s_max[8];
  __shared__ float s_sum[8];

  // split(root key = (0,42)), foldlike: child t = threefry(key; 0, t)
  if (tid >= GT && tid < GT + 2) {
    uint32_t t = tid - GT, o0, o1;
    tf2x32(0u, 42u, 0u, t, o0, o1);
    if (t == 0) { s_kc[0][0] = o0; s_kc[0][1] = o1; }
    else        { s_sub[0][0] = o0; s_sub[0][1] = o1; }
  }

  float mask[NCOL], zacc[NCOL];
  if (worker) {
#pragma unroll
    for (int j = 0; j < NCOL; j++) {
      mask[j] = logits[row * 2048 + tid + j * GT];
      zacc[j] = 0.f;
    }
  }
  __syncthreads();

  const float cc = 2.8853900817779268f;   // 2 * log2(e)   (TAU = 0.5)

  for (int k = 0; k < 1024; k++) {
    const int p = k & 1;
    uint32_t sk0 = s_sub[p][0], sk1 = s_sub[p][1];

    // key wave: compute split(key_k) -> slot p^1 (consumed next iteration)
    if (tid >= GT && tid < GT + 2) {
      uint32_t t = tid - GT, o0, o1;
      tf2x32(s_kc[p][0], s_kc[p][1], 0u, t, o0, o1);
      if (t == 0) { s_kc[p ^ 1][0] = o0; s_kc[p ^ 1][1] = o1; }
      else        { s_sub[p ^ 1][0] = o0; s_sub[p ^ 1][1] = o1; }
    }

    float sv[NCOL];
    float lmax = -3.0e38f;
    if (worker) {
#pragma unroll
      for (int j = 0; j < NCOL; j++) {
        uint32_t idx = (uint32_t)(row * 2048 + tid + j * GT);
        uint32_t b0, b1;
        tf2x32(sk0, sk1, 0u, idx, b0, b1);
        float v = mask[j] + gumbel_from_bits(b0 ^ b1);
        sv[j] = v;
        lmax = fmaxf(lmax, v);
      }
#pragma unroll
      for (int off = 1; off < 64; off <<= 1)
        lmax = fmaxf(lmax, __shfl_xor(lmax, off, 64));
      if (lane == 0) s_max[wid] = lmax;
    }
    __syncthreads();

    float ev[NCOL];
    float ss = 0.f;
    if (worker) {
      float M = s_max[0];
#pragma unroll
      for (int wv = 1; wv < 8; wv++) M = fmaxf(M, s_max[wv]);
      float eM = M * cc;
#pragma unroll
      for (int j = 0; j < NCOL; j++) {
        float e = exp2f(fmaf(sv[j], cc, -eM));
        ev[j] = e;
        ss += e;
      }
#pragma unroll
      for (int off = 1; off < 64; off <<= 1)
        ss += __shfl_xor(ss, off, 64);
      if (lane == 0) s_sum[wid] = ss;
    }
    __syncthreads();

    if (worker) {
      float S = 0.f;
#pragma unroll
      for (int wv = 0; wv < 8; wv++) S += s_sum[wv];
      float r = 1.0f / S;
#pragma unroll
      for (int j = 0; j < NCOL; j++) {
        float m = ev[j] * r;
        mask[j] = m;
        zacc[j] = fmaxf(zacc[j], m);
      }
    }
  }

  if (worker) {
#pragma unroll
    for (int j = 0; j < NCOL; j++)
      z_out[row * 2048 + tid + j * GT] = zacc[j];
  }
}

// ------------------------------- launch ------------------------------------
extern "C" void kernel_launch(void* const* d_in, const int* in_sizes, int n_in,
                              void* d_out, int out_size, void* d_ws, size_t ws_size,
                              hipStream_t stream)
{
  const float* f   = (const float*)d_in[0];
  const float* w1  = (const float*)d_in[1];
  const float* b1  = (const float*)d_in[2];
  const float* g1  = (const float*)d_in[3];
  const float* be1 = (const float*)d_in[4];
  const float* w2  = (const float*)d_in[5];
  const float* b2  = (const float*)d_in[6];
  const float* g2  = (const float*)d_in[7];
  const float* be2 = (const float*)d_in[8];
  const float* w3  = (const float*)d_in[9];
  const float* b3  = (const float*)d_in[10];
  float* out = (float*)d_out;

  // ws layout (floats): partials (16 MB) | h1 (4 MB) | h2 (4 MB) | logits (1 MB)
  float* P      = (float*)d_ws;          // up to 16 * 128 * 2048 = 4 * 128 * 8192
  float* h1     = P + 4194304;
  float* h2     = h1 + 1048576;
  float* logits = h2 + 1048576;

  dim3 blk(256);
  // layer 1: (128,2048) @ (8192,2048)^T, split-K 4 (chunk 512)
  gemm_splitk<<<dim3(64, 4), blk, 0, stream>>>(f, w1, P, 2048, 8192, 512);
  bn_kernel<<<dim3(32), blk, 0, stream>>>(P, 4, 8192, b1, g1, be1, h1, 1);
  // layer 2: (128,8192) @ (8192,8192)^T, split-K 4 (chunk 2048)
  gemm_splitk<<<dim3(64, 4), blk, 0, stream>>>(h1, w2, P, 8192, 8192, 2048);
  bn_kernel<<<dim3(32), blk, 0, stream>>>(P, 4, 8192, b2, g2, be2, h2, 1);
  // layer 3: (128,8192) @ (2048,8192)^T, split-K 16 (chunk 512), BN no affine
  gemm_splitk<<<dim3(16, 16), blk, 0, stream>>>(h2, w3, P, 8192, 2048, 512);
  bn_kernel<<<dim3(8), blk, 0, stream>>>(P, 16, 2048, b3, nullptr, nullptr, logits, 0);
  // gumbel-softmax scan, K=1024
  gumbel_kernel<<<dim3(128), dim3(576), 0, stream>>>(logits, out);
}

// Round 3
// 2588.132 us; speedup vs baseline: 1.4929x; 1.4929x over previous
//
#include <hip/hip_runtime.h>
#include <stdint.h>

// ---------------------------------------------------------------------------
// Masker: 3-layer MLP head (fp32 GEMM + BatchNorm(+ReLU)) then K=1024
// Gumbel-softmax scan with z = running max.
// Round 3: scan restructured (no max-sub, noise pipelined one iter ahead,
// 1 barrier/iter), BN parallelized (register-resident rows), GEMM split-K
// doubled when ws_size permits. PRNG semantics identical to round 2 (passed).
// ---------------------------------------------------------------------------

// ------------------------- Threefry-2x32-20 (JAX) --------------------------
__device__ __forceinline__ uint32_t rotl32(uint32_t v, int r) {
  return (v << r) | (v >> (32 - r));
}

__device__ __forceinline__ void tf2x32(uint32_t k0, uint32_t k1,
                                       uint32_t x0, uint32_t x1,
                                       uint32_t& o0, uint32_t& o1) {
  uint32_t k2 = k0 ^ k1 ^ 0x1BD11BDAu;
  x0 += k0; x1 += k1;
#define TFR(r) { x0 += x1; x1 = rotl32(x1, (r)); x1 ^= x0; }
  TFR(13) TFR(15) TFR(26) TFR(6)   x0 += k1; x1 += k2 + 1u;
  TFR(17) TFR(29) TFR(16) TFR(24)  x0 += k2; x1 += k0 + 2u;
  TFR(13) TFR(15) TFR(26) TFR(6)   x0 += k0; x1 += k1 + 3u;
  TFR(17) TFR(29) TFR(16) TFR(24)  x0 += k1; x1 += k2 + 4u;
  TFR(13) TFR(15) TFR(26) TFR(6)   x0 += k2; x1 += k0 + 5u;
#undef TFR
  o0 = x0; o1 = x1;
}

// Returns g * cc where g = -ln(-ln u), cc = 2*log2(e)  (TAU=0.5).
// g*cc = -2*log2(-log2 u) + cc*(-ln ln 2);  cc*ln2 == 2 exactly.
__device__ __forceinline__ float gumbel_cc(uint32_t bits) {
  float u = __uint_as_float((bits >> 9) | 0x3f800000u) - 1.0f;
  u = fmaxf(u, 1.17549435e-38f);
  float l = __log2f(u);            // < 0
  float t = __log2f(-l);
  return fmaf(-2.0f, t, 1.0575327458538905f);
}

// ------------------------------- GEMM --------------------------------------
// C_partial[slice][b][n] = sum_{k in chunk} A[b,k] * W[n,k]
// A: (128, K) row-major, W: (N, K) row-major. Tile 128x128, BK=16.
#define BK 16

__global__ __launch_bounds__(256) void gemm_splitk(
    const float* __restrict__ A, const float* __restrict__ W,
    float* __restrict__ P, int K, int N, int kchunk)
{
  __shared__ float sA[BK][132];   // [k][b], +4 pad keeps 16B alignment
  __shared__ float sW[BK][132];   // [k][n]
  const int tid = threadIdx.x;
  const int n0 = blockIdx.x * 128;
  const int k0 = blockIdx.y * kchunk;
  const int tx = tid & 15;        // n-group: n = n0 + tx*8 ..
  const int ty = tid >> 4;        // b-group: b = ty*8 ..

  float acc[8][8];
#pragma unroll
  for (int i = 0; i < 8; i++)
#pragma unroll
    for (int j = 0; j < 8; j++) acc[i][j] = 0.f;

  for (int kt = k0; kt < k0 + kchunk; kt += BK) {
#pragma unroll
    for (int i = 0; i < 2; i++) {
      int q = tid * 2 + i;        // 0..511
      int row = q >> 2;           // 0..127
      int kk = (q & 3) * 4;       // 0,4,8,12
      float4 av = *(const float4*)(A + (size_t)row * K + kt + kk);
      sA[kk + 0][row] = av.x; sA[kk + 1][row] = av.y;
      sA[kk + 2][row] = av.z; sA[kk + 3][row] = av.w;
      float4 wv = *(const float4*)(W + (size_t)(n0 + row) * K + kt + kk);
      sW[kk + 0][row] = wv.x; sW[kk + 1][row] = wv.y;
      sW[kk + 2][row] = wv.z; sW[kk + 3][row] = wv.w;
    }
    __syncthreads();
#pragma unroll
    for (int kk = 0; kk < BK; kk++) {
      float a[8], w[8];
#pragma unroll
      for (int i = 0; i < 8; i++) a[i] = sA[kk][ty * 8 + i];
#pragma unroll
      for (int j = 0; j < 8; j++) w[j] = sW[kk][tx * 8 + j];
#pragma unroll
      for (int i = 0; i < 8; i++)
#pragma unroll
        for (int j = 0; j < 8; j++)
          acc[i][j] = fmaf(a[i], w[j], acc[i][j]);
    }
    __syncthreads();
  }

  float* Ps = P + (size_t)blockIdx.y * 128 * N;
#pragma unroll
  for (int i = 0; i < 8; i++) {
    int b = ty * 8 + i;
#pragma unroll
    for (int j = 0; j < 8; j += 4) {
      float4 v = make_float4(acc[i][j], acc[i][j + 1], acc[i][j + 2], acc[i][j + 3]);
      *(float4*)(Ps + (size_t)b * N + n0 + tx * 8 + j) = v;
    }
  }
}

// ------------------------------ BatchNorm ----------------------------------
// Single pass over P: per-thread row values kept in registers; cross-rowgroup
// stats reduced via LDS. Block = 256 threads = CPB cols x (256/CPB) rowgroups.
template <int CPB>
__global__ __launch_bounds__(256) void bn_kernel(
    const float* __restrict__ P, int nsl, int N,
    const float* __restrict__ bias, const float* __restrict__ gamma,
    const float* __restrict__ beta, float* __restrict__ out, int relu)
{
  constexpr int R = 256 / CPB;     // rowgroups
  constexpr int NR = 128 / R;      // rows per thread
  const int cl = threadIdx.x % CPB;
  const int rg = threadIdx.x / CPB;
  const int c = blockIdx.x * CPB + cl;
  const int r0 = rg * NR;

  float bc = bias ? bias[c] : 0.f;
  float xs[NR];
  float s = 0.f, s2 = 0.f;
#pragma unroll
  for (int i = 0; i < NR; i++) {
    float x = bc;
    for (int t = 0; t < nsl; t++)
      x += P[((size_t)t * 128 + r0 + i) * N + c];
    xs[i] = x; s += x; s2 += x * x;
  }

  __shared__ float sh_s[R][CPB], sh_s2[R][CPB];
  sh_s[rg][cl] = s; sh_s2[rg][cl] = s2;
  __syncthreads();
  float S = 0.f, S2 = 0.f;
#pragma unroll
  for (int g = 0; g < R; g++) { S += sh_s[g][cl]; S2 += sh_s2[g][cl]; }

  float mu = S * (1.f / 128.f);
  float var = S2 * (1.f / 128.f) - mu * mu;
  float rstd = rsqrtf(var + 1e-5f);
  float ga = gamma ? gamma[c] : 1.f;
  float be = beta ? beta[c] : 0.f;
  float scale = rstd * ga;
  float shift = be - mu * scale;
#pragma unroll
  for (int i = 0; i < NR; i++) {
    float y = fmaf(xs[i], scale, shift);
    if (relu) y = fmaxf(y, 0.f);
    out[(size_t)(r0 + i) * N + c] = y;
  }
}

// ----------------------------- Gumbel scan ---------------------------------
// One block per row. 512 work threads (8 waves) x 4 cols; wave 8 runs the
// serial key chain one split ahead. Gumbel noise for iteration k+1 is
// generated during iteration k (it is mask-independent), filling the barrier
// wait. No max-subtraction: (mask+g)*cc <= ~51 in log2 domain -> exp2 and the
// row sum stay far below fp32 overflow. One barrier per iteration.
#define GT 512
#define NCOL 4

__global__ __launch_bounds__(576) void gumbel_kernel(
    const float* __restrict__ logits, float* __restrict__ z_out)
{
  const int tid = threadIdx.x;
  const int row = blockIdx.x;             // 0..127
  const int wid = tid >> 6;
  const int lane = tid & 63;
  const bool worker = tid < GT;

  __shared__ uint32_t s_sub[2][2];        // [slot][word]
  __shared__ float s_sum[2][8];           // [parity][wave]

  const float cc = 2.8853900817779268f;   // 2*log2(e)

  // Prologue: split(root=(0,42)) -> K_0 (child 0), sub_0 (child 1).
  uint32_t K0a, K0b, S0a, S0b;
  tf2x32(0u, 42u, 0u, 0u, K0a, K0b);
  tf2x32(0u, 42u, 0u, 1u, S0a, S0b);

  float mask[NCOL], gcc[NCOL], zacc[NCOL];
  uint32_t Ka = K0a, Kb = K0b;            // key-wave: current key = K_{k+1}

  if (worker) {
#pragma unroll
    for (int j = 0; j < NCOL; j++) {
      int c = tid + j * GT;
      mask[j] = logits[row * 2048 + c];
      zacc[j] = 0.f;
      uint32_t b0, b1;
      tf2x32(S0a, S0b, 0u, (uint32_t)(row * 2048 + c), b0, b1);
      gcc[j] = gumbel_cc(b0 ^ b1);        // g_0 * cc
    }
  } else {
    // key wave: split(K_0) -> K_1 (broadcast), sub_1 -> slot 1
    uint32_t t = (uint32_t)(tid - GT), o0, o1;
    tf2x32(Ka, Kb, 0u, t, o0, o1);
    if (t == 1u) { s_sub[1][0] = o0; s_sub[1][1] = o1; }
    Ka = __shfl(o0, 0, 64);
    Kb = __shfl(o1, 0, 64);
  }
  __syncthreads();

  for (int k = 0; k < 1024; k++) {
    const int p = k & 1;
    if (worker) {
      // sub_{k+1}, written by key wave >= 1 barrier ago
      uint32_t sk0 = s_sub[(k + 1) & 1][0];
      uint32_t sk1 = s_sub[(k + 1) & 1][1];

      float ev[NCOL];
      float ss = 0.f;
#pragma unroll
      for (int j = 0; j < NCOL; j++) {
        float e = exp2f(fmaf(mask[j], cc, gcc[j]));
        ev[j] = e; ss += e;
      }
#pragma unroll
      for (int off = 1; off < 64; off <<= 1)
        ss += __shfl_xor(ss, off, 64);
      if (lane == 0) s_sum[p][wid] = ss;

      // generate g_{k+1}*cc now — independent work that hides the barrier
#pragma unroll
      for (int j = 0; j < NCOL; j++) {
        uint32_t idx = (uint32_t)(row * 2048 + tid + j * GT);
        uint32_t b0, b1;
        tf2x32(sk0, sk1, 0u, idx, b0, b1);
        gcc[j] = gumbel_cc(b0 ^ b1);
      }
      __syncthreads();

      float S = 0.f;
#pragma unroll
      for (int wv = 0; wv < 8; wv++) S += s_sum[p][wv];
      float r = 1.0f / S;
#pragma unroll
      for (int j = 0; j < NCOL; j++) {
        float m = ev[j] * r;
        mask[j] = m;
        zacc[j] = fmaxf(zacc[j], m);
      }
    } else {
      // key wave: split(K_{k+1}) -> K_{k+2}, sub_{k+2} -> slot [k&1]
      uint32_t t = (uint32_t)(tid - GT), o0, o1;
      tf2x32(Ka, Kb, 0u, t, o0, o1);
      if (t == 1u) { s_sub[p][0] = o0; s_sub[p][1] = o1; }
      Ka = __shfl(o0, 0, 64);
      Kb = __shfl(o1, 0, 64);
      __syncthreads();
    }
  }

  if (worker) {
#pragma unroll
    for (int j = 0; j < NCOL; j++)
      z_out[row * 2048 + tid + j * GT] = zacc[j];
  }
}

// ------------------------------- launch ------------------------------------
extern "C" void kernel_launch(void* const* d_in, const int* in_sizes, int n_in,
                              void* d_out, int out_size, void* d_ws, size_t ws_size,
                              hipStream_t stream)
{
  const float* f   = (const float*)d_in[0];
  const float* w1  = (const float*)d_in[1];
  const float* b1  = (const float*)d_in[2];
  const float* g1  = (const float*)d_in[3];
  const float* be1 = (const float*)d_in[4];
  const float* w2  = (const float*)d_in[5];
  const float* b2  = (const float*)d_in[6];
  const float* g2  = (const float*)d_in[7];
  const float* be2 = (const float*)d_in[8];
  const float* w3  = (const float*)d_in[9];
  const float* b3  = (const float*)d_in[10];
  float* out = (float*)d_out;

  // ws layout (floats): h1 (4MB) | h2 (4MB) | logits (1MB) | P
  float* h1     = (float*)d_ws;
  float* h2     = h1 + 1048576;
  float* logits = h2 + 1048576;
  float* P      = logits + 262144;

  // adaptive split-K: big config needs P = 8*128*8192 floats (43 MB total)
  const size_t need_big = (size_t)(2359296 + 8388608) * 4;
  const int s12 = (ws_size >= need_big) ? 8 : 4;   // gemm1/2 slices
  const int s3  = (ws_size >= need_big) ? 32 : 16; // gemm3 slices

  dim3 blk(256);
  // layer 1: (128,2048) @ (8192,2048)^T
  gemm_splitk<<<dim3(64, s12), blk, 0, stream>>>(f, w1, P, 2048, 8192, 2048 / s12);
  bn_kernel<64><<<dim3(128), blk, 0, stream>>>(P, s12, 8192, b1, g1, be1, h1, 1);
  // layer 2: (128,8192) @ (8192,8192)^T
  gemm_splitk<<<dim3(64, s12), blk, 0, stream>>>(h1, w2, P, 8192, 8192, 8192 / s12);
  bn_kernel<64><<<dim3(128), blk, 0, stream>>>(P, s12, 8192, b2, g2, be2, h2, 1);
  // layer 3: (128,8192) @ (2048,8192)^T, BN no affine
  gemm_splitk<<<dim3(16, s3), blk, 0, stream>>>(h2, w3, P, 8192, 2048, 8192 / s3);
  bn_kernel<32><<<dim3(64), blk, 0, stream>>>(P, s3, 2048, b3, nullptr, nullptr, logits, 0);
  // gumbel-softmax scan, K=1024
  gumbel_kernel<<<dim3(128), dim3(576), 0, stream>>>(logits, out);
}